// Round 7
// baseline (118.294 us; speedup 1.0000x reference)
//
#include <hip/hip_runtime.h>

#define N_TOTAL 32768
#define D_DIM   512
#define C_DIM   64
#define K_DIM   16
#define M_DIM   128
#define NODES_  15
#define ROWS_B  32          // rows per block (grid = 1024)

typedef unsigned short u16;
typedef unsigned int   u32;
typedef unsigned long long u64;
typedef unsigned char  u8;
typedef float  f32x4   __attribute__((ext_vector_type(4)));
typedef short  short8v __attribute__((ext_vector_type(8)));

#define WAIT_VM(N) asm volatile("s_waitcnt vmcnt(" #N ")" ::: "memory")

__device__ __forceinline__ u32 f2bf_bits(float f) {
    u32 u = __float_as_uint(f);
    return (u + 0x7FFFu + ((u >> 16) & 1u)) >> 16;   // RNE
}

// coalesced global -> LDS direct copy, 16 B/lane (wave-uniform LDS base)
__device__ __forceinline__ void gload_lds16(const float* g, float* l) {
    __builtin_amdgcn_global_load_lds(
        (const __attribute__((address_space(1))) void*)g,
        (__attribute__((address_space(3))) void*)l, 16, 0, 0);
}

// ---------------------------------------------------------------------------
// Kernel 1 (unchanged, r4-verified): Lbf = L in MFMA-B-fragment order, bf16.
// Fragment (ct, ch): lane holds B[k][n], n = ct*16 + (lane&15),
// k = ch*32 + (lane>>4)*8 + i. Layout [ct][ch][lane][8] -> 1 KB coalesced
// wave reads in the gemm. 256 KB, L2-resident per XCD.
// ---------------------------------------------------------------------------
__global__ __launch_bounds__(256) void build_lbf(
    const float* __restrict__ L, u16* __restrict__ Lbf)
{
    int idx  = blockIdx.x * 256 + threadIdx.x;   // 16384 threads = 64 blocks
    int lane = idx & 63;
    int ch   = (idx >> 6) & 31;
    int ct   = idx >> 11;                        // 0..7
    int m  = ct * 16 + (lane & 15);
    int k0 = ch * 32 + ((lane >> 4) * 8);
    const float* src = L + (size_t)m * 1024 + k0;
    float4 a = *(const float4*)(src);
    float4 b = *(const float4*)(src + 4);
    u32 w0 = f2bf_bits(a.x) | (f2bf_bits(a.y) << 16);
    u32 w1 = f2bf_bits(a.z) | (f2bf_bits(a.w) << 16);
    u32 w2 = f2bf_bits(b.x) | (f2bf_bits(b.y) << 16);
    u32 w3 = f2bf_bits(b.z) | (f2bf_bits(b.w) << 16);
    *(uint4*)(Lbf + (size_t)idx * 8) = make_uint4(w0, w1, w2, w3);
}

// ---------------------------------------------------------------------------
// Kernel 2 (megakernel, r6-verified structure at half tile -> 4 blocks/CU):
// 32 rows/block, 4 waves, 16 waves/CU resident.
// Codes phase: 4 chunks of 8 rows, double-buffered per-wave sI regions;
// chunk ci+1's 4 gload_lds16 issued BEFORE the counted WAIT_VM(4) on chunk
// ci (r6-verified pipeline). Wave descends its own 2 rows/chunk.
// Codes accumulate in registers; one write phase, sC2 stride 36 B/cls:
// write banks = 9*lane mod 32 (2-way = free), read = 16 banks x 1 dword.
// Gemm phase: r4/r5/r6-verified MFMA body, wave = 2 row-tiles x 2 col-tiles.
// A = synthesized one-hot; B = coalesced Lbf frags. C/D: col=lane&15,
// row=(lane>>4)*4+j (m89). h==0 -> bit 0 == argmax first-max tie rule.
// ---------------------------------------------------------------------------
__global__ __launch_bounds__(256, 4) void mega_kernel(
    const float* __restrict__ I,
    const float* __restrict__ T,
    const int* __restrict__ dims,
    const u16* __restrict__ Lbf,
    float* __restrict__ out)
{
    __shared__ float sI[2 * 8 * D_DIM];     // 32 KB dbuf, wave wv -> +wv*1024
    __shared__ float sT[C_DIM * NODES_];    // 3.75 KB
    __shared__ u8    sC2[C_DIM * 36];       // 2.25 KB: [cls]{36}[l15] u16{rt0,rt1}

    const int tid  = threadIdx.x;
    const int lane = tid & 63;              // class c in codes phase
    const int wv   = tid >> 6;
    const int rowBase = blockIdx.x * ROWS_B;

    // per-lane dim indices: one coalesced int4 (1 KB, L2-hot)
    const int4 dml = ((const int4*)dims)[lane];

    auto issue = [&](int ci, int buf) {     // stage this wave's 2 rows of chunk ci
        const float* src = I + (size_t)(rowBase + ci * 8 + wv * 2) * D_DIM;
        float* dst = sI + buf * 8 * D_DIM + wv * 2 * D_DIM;
        #pragma unroll
        for (int i = 0; i < 4; ++i)
            gload_lds16(src + i * 256 + lane * 4, dst + i * 256);
    };

    // c4[rr][p]: byte rt = code of row (rt*2+p)*8 + wv*2 + rr
    u32 c4[2][2] = {{0u, 0u}, {0u, 0u}};
    const float* tc = sT + lane * NODES_;

    auto descend = [&](int buf, int ci) {
        const int rt = ci >> 1, p = ci & 1;
        #pragma unroll
        for (int rr = 0; rr < 2; ++rr) {
            const float* v = sI + buf * 8 * D_DIM + (wv * 2 + rr) * D_DIM;
            float x0 = v[dml.x], x1 = v[dml.y], x2 = v[dml.z], x3 = v[dml.w];
            int node = 0, k = 0;
            int b0 = (x0 - tc[0] > 0.0f) ? 1 : 0;
            k = b0; node = 1 + b0;
            int b1 = (x1 - tc[node] > 0.0f) ? 1 : 0;
            k = (k << 1) | b1; node = (node << 1) + 1 + b1;
            int b2 = (x2 - tc[node] > 0.0f) ? 1 : 0;
            k = (k << 1) | b2; node = (node << 1) + 1 + b2;
            int b3 = (x3 - tc[node] > 0.0f) ? 1 : 0;
            k = (k << 1) | b3;
            c4[rr][p] |= (u32)k << (8 * rt);
        }
    };

    // prologue: chunk 0 staged under the sT fill; barrier drains it
    issue(0, 0);
    for (int j = tid; j < C_DIM * NODES_; j += 256) sT[j] = T[j];
    __syncthreads();                // sT ready, chunk-0 resident
    issue(1, 1);                    // chunk 1 in flight across descent 0

    descend(0, 0);
    issue(2, 0);                    // buf0 (chunk 0) already consumed
    WAIT_VM(4);                     // chunk 1 done, chunk 2 in flight
    descend(1, 1);
    issue(3, 1);
    WAIT_VM(4);                     // chunk 2 done, chunk 3 in flight
    descend(0, 2);
    WAIT_VM(0);                     // chunk 3 done
    descend(1, 3);

    // code-write phase: 4 u16 writes/lane, banks 9*lane mod 32 (2-way, free)
    #pragma unroll
    for (int p = 0; p < 2; ++p)
        #pragma unroll
        for (int rr = 0; rr < 2; ++rr)
            *(u16*)(sC2 + lane * 36 + (p * 8 + wv * 2 + rr) * 2) =
                (u16)c4[rr][p];
    __syncthreads();                // sC2 complete, all waves

    // ---- gemm phase (verified structure, 2 rt x 2 ct per wave) ----
    const int l15     = lane & 15;
    const int clsLane = (lane >> 5) & 1;        // which class of the k-chunk
    const int kb      = ((lane >> 4) & 1) * 8;  // k-offset within the class

    f32x4 acc[2][2] = {};

    const u16* lb0 = Lbf + ((size_t)(wv * 2 + 0) * 32 * 64 + lane) * 8;
    const u16* lb1 = Lbf + ((size_t)(wv * 2 + 1) * 32 * 64 + lane) * 8;

    #pragma unroll 4
    for (int ch = 0; ch < 32; ++ch) {
        union { uint4 u; short8v v; } b0, b1;
        b0.u = *(const uint4*)(lb0 + (size_t)ch * 64 * 8);
        b1.u = *(const uint4*)(lb1 + (size_t)ch * 64 * 8);
        const int cls = ch * 2 + clsLane;
        // both row-tiles' codes for (cls, l15): one conflict-free u16 read
        const u32 codes2 = *(const u16*)(sC2 + cls * 36 + l15 * 2);
        #pragma unroll
        for (int rt = 0; rt < 2; ++rt) {
            u32 cd = (codes2 >> (8 * rt)) & 0xFFu;
            u32 tt = cd - (u32)kb;              // one-hot slot if 0..7
            u64 sv = 0x3F80ull << ((tt & 3) * 16);
            union { u64 d[2]; short8v v; } a;
            a.d[0] = (tt < 4) ? sv : 0ull;
            a.d[1] = (tt >= 4 && tt < 8) ? sv : 0ull;
            acc[rt][0] = __builtin_amdgcn_mfma_f32_16x16x32_bf16(
                             a.v, b0.v, acc[rt][0], 0, 0, 0);
            acc[rt][1] = __builtin_amdgcn_mfma_f32_16x16x32_bf16(
                             a.v, b1.v, acc[rt][1], 0, 0, 0);
        }
    }

    // epilogue: D row = (lane>>4)*4 + j, col = lane&15 (within 16x16 tile)
    #pragma unroll
    for (int rt = 0; rt < 2; ++rt) {
        #pragma unroll
        for (int cj = 0; cj < 2; ++cj) {
            int col = (wv * 2 + cj) * 16 + l15;
            int r0  = rowBase + rt * 16 + ((lane >> 4) << 2);
            float* o = out + (size_t)r0 * M_DIM + col;
            o[0 * M_DIM] = acc[rt][cj][0];
            o[1 * M_DIM] = acc[rt][cj][1];
            o[2 * M_DIM] = acc[rt][cj][2];
            o[3 * M_DIM] = acc[rt][cj][3];
        }
    }
}

extern "C" void kernel_launch(void* const* d_in, const int* in_sizes, int n_in,
                              void* d_out, int out_size, void* d_ws, size_t ws_size,
                              hipStream_t stream) {
    // inputs: I(0) T(1) L(2) S(3) B(4) dims(5) temp(6) — fp32, dims int32
    const float* I    = (const float*)d_in[0];
    const float* T    = (const float*)d_in[1];
    const float* L    = (const float*)d_in[2];
    const int*   dims = (const int*)d_in[5];

    u16* Lbf = (u16*)d_ws;                      // 256 KB, fragment-ordered

    hipLaunchKernelGGL(build_lbf, dim3(64), dim3(256), 0, stream, L, Lbf);
    hipLaunchKernelGGL(mega_kernel, dim3(N_TOTAL / ROWS_B), dim3(256), 0, stream,
                       I, T, dims, Lbf, (float*)d_out);
}